// Round 10
// baseline (324.578 us; speedup 1.0000x reference)
//
#include <hip/hip_runtime.h>
#include <hip/hip_fp16.h>

// ---------------------------------------------------------------------------
// GCN 2-layer forward:  out = log_softmax( A_hat * relu(A_hat * (x W1) + b1) W2 + b2 )
// A_hat = D^-1/2 (A + I) D^-1/2, deg on dst. Edge index arrives as int32.
//
// R10: gemm2 fused into pull1. pull1 blocks = 1024 thr = 16 waves = 16 nodes;
// h rows go to LDS (never global), then waves 0-3 run MFMA 16x16x32_f16
// against L2-resident swizzled W2 and emit T2' = dinv*(h W2) directly.
// Kills the 51MB h round-trip + one dispatch. CSR build, gemm1(MFMA),
// pull2 unchanged from r9.
// ---------------------------------------------------------------------------

#define BSHIFT 9
#define BSIZE  512            // nodes per bucket; NB = ceil(N/512) = 196 < 256
#define P2_T   1024
#define P2_I   16             // edges staged per thread in partition pass

using half8 = __attribute__((ext_vector_type(8))) _Float16;
using f32x4 = __attribute__((ext_vector_type(4))) float;

// --- pass 1: per-bucket edge counts (coalesced dst read, LDS histogram) ----
__global__ __launch_bounds__(256) void bucket_hist_kernel(const int* __restrict__ dst, int E,
                                                          unsigned int* __restrict__ bcount, int NB) {
    __shared__ unsigned int h[256];
    int t = threadIdx.x;
    h[t] = 0u;
    __syncthreads();
    for (int i = blockIdx.x * 256 + t; i < E; i += gridDim.x * 256)
        atomicAdd(&h[dst[i] >> BSHIFT], 1u);
    __syncthreads();
    if (t < NB && h[t]) atomicAdd(&bcount[t], h[t]);
}

// --- scan bucket counts -> bucket_base bb[0..NB], bucket_fill bf -----------
__global__ __launch_bounds__(256) void bucket_scan_kernel(const unsigned int* __restrict__ bcount,
                                                          unsigned int* __restrict__ bb,
                                                          unsigned int* __restrict__ bf,
                                                          int NB, int E) {
    __shared__ unsigned int s[256];
    int t = threadIdx.x;
    unsigned int v = (t < NB) ? bcount[t] : 0u;
    s[t] = v;
    __syncthreads();
    for (int off = 1; off < 256; off <<= 1) {
        unsigned int u = s[t];
        if (t >= off) u += s[t - off];
        __syncthreads();
        s[t] = u;
        __syncthreads();
    }
    if (t < NB) {
        unsigned int ex = s[t] - v;
        bb[t] = ex;
        bf[t] = ex;
    }
    if (t == 0) bb[NB] = (unsigned int)E;
}

// --- pass 2: partition edges into dst-buckets, packed src|dstLocal<<17 -----
__global__ __launch_bounds__(1024) void partition_kernel(const int* __restrict__ src,
                                                         const int* __restrict__ dst,
                                                         unsigned int* __restrict__ bucket_fill,
                                                         unsigned int* __restrict__ ebuf,
                                                         int E, int NB) {
    __shared__ unsigned int hist[256];
    __shared__ unsigned int cur[256];
    int t = threadIdx.x;
    if (t < 256) hist[t] = 0u;
    __syncthreads();
    size_t base = (size_t)blockIdx.x * (P2_T * P2_I);
    int sv[P2_I], dv[P2_I];
#pragma unroll
    for (int i = 0; i < P2_I; ++i) {
        size_t idx = base + (size_t)i * P2_T + t;
        if (idx < (size_t)E) {
            sv[i] = src[idx];
            dv[i] = dst[idx];
            atomicAdd(&hist[dv[i] >> BSHIFT], 1u);
        } else dv[i] = -1;
    }
    __syncthreads();
    if (t < NB && hist[t] > 0u) cur[t] = atomicAdd(&bucket_fill[t], hist[t]);
    __syncthreads();
#pragma unroll
    for (int i = 0; i < P2_I; ++i) {
        if (dv[i] >= 0) {
            int b = dv[i] >> BSHIFT;
            unsigned int pos = atomicAdd(&cur[b], 1u);
            ebuf[pos] = (unsigned int)sv[i] | ((unsigned int)(dv[i] & (BSIZE - 1)) << 17);
        }
    }
}

// --- pass 3: per-bucket deg/dinv/rowptr in LDS + scatter; cursor=rowend ----
__global__ __launch_bounds__(256) void bucket_scatter2_kernel(const unsigned int* __restrict__ ebuf,
                                                              const unsigned int* __restrict__ bb,
                                                              unsigned int* __restrict__ cursor,
                                                              unsigned int* __restrict__ deg,
                                                              float* __restrict__ dinv,
                                                              int* __restrict__ col, int N) {
    __shared__ unsigned int ldeg[BSIZE];
    __shared__ unsigned int lcur[BSIZE];
    __shared__ unsigned int part[256];
    int b = blockIdx.x, t = threadIdx.x;
    int node0 = b << BSHIFT;
    int nn = min(BSIZE, N - node0);
    ldeg[t] = 0u;
    ldeg[t + 256] = 0u;
    __syncthreads();
    unsigned int e0 = bb[b], e1 = bb[b + 1];
    for (unsigned int e = e0 + t; e < e1; e += 256)
        atomicAdd(&ldeg[ebuf[e] >> 17], 1u);
    __syncthreads();
    unsigned int a0 = ldeg[2 * t], a1 = ldeg[2 * t + 1];
    part[t] = a0 + a1;
    __syncthreads();
    for (int off = 1; off < 256; off <<= 1) {
        unsigned int u = part[t];
        if (t >= off) u += part[t - off];
        __syncthreads();
        part[t] = u;
        __syncthreads();
    }
    unsigned int ex = part[t] - (a0 + a1);
    lcur[2 * t]     = e0 + ex;
    lcur[2 * t + 1] = e0 + ex + a0;
    __syncthreads();
    for (unsigned int e = e0 + t; e < e1; e += 256) {
        unsigned int p = ebuf[e];
        unsigned int pos = atomicAdd(&lcur[p >> 17], 1u);
        col[pos] = (int)(p & 0x1FFFFu);
    }
    __syncthreads();
    for (int i = t; i < nn; i += 256) {
        unsigned int d = ldeg[i];
        deg[node0 + i] = d;
        dinv[node0 + i] = rsqrtf((float)(d + 1u));
        cursor[node0 + i] = lcur[i];
    }
}

// --- swizzle W1 (128x128) and W2 (128x64) into MFMA B-fragment order -------
// w1s[((c*4+s)*64+l)*8+j] = W[k][n], k=(l>>4)*8+j+32s, n=16c+(l&15)
__global__ __launch_bounds__(256) void swizzle_w_kernel(const float* __restrict__ W1,
                                                        const float* __restrict__ W2,
                                                        __half* __restrict__ w1s,
                                                        __half* __restrict__ w2s) {
    int t = threadIdx.x;
    for (int i = t; i < 8 * 4 * 64 * 8; i += 256) {   // W1: 8 col-tiles
        int j = i & 7, l = (i >> 3) & 63, s = (i >> 9) & 3, c = i >> 11;
        int k = ((l >> 4) * 8) + j + 32 * s;
        int nn = 16 * c + (l & 15);
        w1s[i] = __float2half(W1[k * 128 + nn]);
    }
    for (int i = t; i < 4 * 4 * 64 * 8; i += 256) {   // W2: 4 col-tiles
        int j = i & 7, l = (i >> 3) & 63, s = (i >> 9) & 3, c = i >> 11;
        int k = ((l >> 4) * 8) + j + 32 * s;
        int nn = 16 * c + (l & 15);
        w2s[i] = __float2half(W2[k * 64 + nn]);
    }
}

// --- GEMM1 (MFMA): Y[r,128] = f16( dinv[r] * (X[r,128] @ W1) ), X fp32 -----
__global__ __launch_bounds__(256) void gemm1_mfma_kernel(const float* __restrict__ X,
                                                         const __half* __restrict__ w1s,
                                                         const float* __restrict__ dinv,
                                                         __half* __restrict__ Y, int n) {
    int t = threadIdx.x;
    int wave = t >> 6, lane = t & 63;
    int quad = lane >> 4, m = lane & 15;
    int rowbase = blockIdx.x * 64 + wave * 16;
    int arow = rowbase + m;
    bool aok = arow < n;
    const float* xr = X + (size_t)arow * 128 + quad * 8;

    half8 afrag[4];
#pragma unroll
    for (int s = 0; s < 4; ++s) {
        float4 p0 = make_float4(0.f, 0.f, 0.f, 0.f), p1 = p0;
        if (aok) {
            p0 = *(const float4*)(xr + s * 32);
            p1 = *(const float4*)(xr + s * 32 + 4);
        }
        afrag[s][0] = (_Float16)p0.x; afrag[s][1] = (_Float16)p0.y;
        afrag[s][2] = (_Float16)p0.z; afrag[s][3] = (_Float16)p0.w;
        afrag[s][4] = (_Float16)p1.x; afrag[s][5] = (_Float16)p1.y;
        afrag[s][6] = (_Float16)p1.z; afrag[s][7] = (_Float16)p1.w;
    }

    const half8* bp = (const half8*)w1s;
    f32x4 acc[8];
#pragma unroll
    for (int c = 0; c < 8; ++c) acc[c] = (f32x4){0.f, 0.f, 0.f, 0.f};
#pragma unroll
    for (int c = 0; c < 8; ++c)
#pragma unroll
        for (int s = 0; s < 4; ++s)
            acc[c] = __builtin_amdgcn_mfma_f32_16x16x32_f16(afrag[s], bp[(c * 4 + s) * 64 + lane], acc[c], 0, 0, 0);

#pragma unroll
    for (int i = 0; i < 4; ++i) {
        int row = rowbase + quad * 4 + i;
        if (row < n) {
            float w = dinv[row];
            __half* yr = Y + (size_t)row * 128 + m;
#pragma unroll
            for (int c = 0; c < 8; ++c) yr[c * 16] = __float2half(acc[c][i] * w);
        }
    }
}

// --- pull1 + gemm2 fused: 16 waves = 16 nodes; h -> LDS; MFMA -> T2' -------
// h[d] = relu(dinv[d]*(T1'[d] + sum T1'[col]) + b1)   (LDS only)
// T2'[d] = f16( dinv[d] * (h[d] @ W2) )
#define HSTRIDE 136   // halves per LDS row: 272B = 17*16B -> half8 loads aligned
__global__ __launch_bounds__(1024) void pull1_fused_kernel(const __half* __restrict__ T,
                                                           const int* __restrict__ col,
                                                           const unsigned int* __restrict__ cursor,
                                                           const unsigned int* __restrict__ deg,
                                                           const float* __restrict__ dinv,
                                                           const float* __restrict__ b1,
                                                           const __half* __restrict__ w2s,
                                                           __half* __restrict__ Y, int N) {
    __shared__ __half hl[16 * HSTRIDE];
    int t = threadIdx.x;
    int wave = t >> 6, lane = t & 63;
    int node0 = blockIdx.x * 16;
    int node = node0 + wave;

    if (node < N) {
        unsigned int end = cursor[node];
        unsigned int e = end - deg[node];
        const __half2* Tv = (const __half2*)T;      // row stride 64 half2
        float2 acc = __half22float2(Tv[(size_t)node * 64 + lane]);   // self loop
        for (; e + 3 < end; e += 4) {               // 4 loads in flight
            int s0 = col[e], s1 = col[e + 1], s2 = col[e + 2], s3 = col[e + 3];
            float2 v0 = __half22float2(Tv[(size_t)s0 * 64 + lane]);
            float2 v1 = __half22float2(Tv[(size_t)s1 * 64 + lane]);
            float2 v2 = __half22float2(Tv[(size_t)s2 * 64 + lane]);
            float2 v3 = __half22float2(Tv[(size_t)s3 * 64 + lane]);
            acc.x += (v0.x + v1.x) + (v2.x + v3.x);
            acc.y += (v0.y + v1.y) + (v2.y + v3.y);
        }
        for (; e < end; ++e) {
            float2 v0 = __half22float2(Tv[(size_t)col[e] * 64 + lane]);
            acc.x += v0.x; acc.y += v0.y;
        }
        float w = dinv[node];
        float2 b = ((const float2*)b1)[lane];
        float hx = fmaxf(fmaf(w, acc.x, b.x), 0.f);
        float hy = fmaxf(fmaf(w, acc.y, b.y), 0.f);
        ((__half2*)(hl + wave * HSTRIDE))[lane] = __floats2half2_rn(hx, hy);
    } else {
        ((__half2*)(hl + wave * HSTRIDE))[lane] = __floats2half2_rn(0.f, 0.f);
    }
    __syncthreads();

    // waves 0-3: MFMA h(16x128) @ W2(128x64); wave c computes col-tile c.
    if (wave < 4) {
        int quad = lane >> 4, m = lane & 15;
        half8 afrag[4];
#pragma unroll
        for (int s = 0; s < 4; ++s)
            afrag[s] = *(const half8*)(hl + m * HSTRIDE + quad * 8 + s * 32);
        const half8* bp = (const half8*)w2s;
        f32x4 acc = (f32x4){0.f, 0.f, 0.f, 0.f};
#pragma unroll
        for (int s = 0; s < 4; ++s)
            acc = __builtin_amdgcn_mfma_f32_16x16x32_f16(afrag[s], bp[(wave * 4 + s) * 64 + lane], acc, 0, 0, 0);
#pragma unroll
        for (int i = 0; i < 4; ++i) {
            int row = node0 + quad * 4 + i;
            if (row < N) {
                float w = dinv[row];
                Y[(size_t)row * 64 + wave * 16 + m] = __float2half(acc[i] * w);
            }
        }
    }
}

// --- pull layer 2 + logsoftmax: out[d] = lsm(dinv[d]*sum + b2), F=64 -------
__global__ __launch_bounds__(256) void pull_agg2_kernel(const __half* __restrict__ T,
                                                        const int* __restrict__ col,
                                                        const unsigned int* __restrict__ cursor,
                                                        const unsigned int* __restrict__ deg,
                                                        const float* __restrict__ dinv,
                                                        const float* __restrict__ b2,
                                                        float* __restrict__ OUT, int N) {
    int node = blockIdx.x * 8 + (threadIdx.x >> 5);
    if (node >= N) return;
    int c2 = threadIdx.x & 31;                  // col pair
    unsigned int end = cursor[node];
    unsigned int e = end - deg[node];
    const __half2* Tv = (const __half2*)T;      // row stride 32 half2
    float2 acc = __half22float2(Tv[(size_t)node * 32 + c2]);     // self loop
    for (; e + 3 < end; e += 4) {
        float2 v0 = __half22float2(Tv[(size_t)col[e] * 32 + c2]);
        float2 v1 = __half22float2(Tv[(size_t)col[e + 1] * 32 + c2]);
        float2 v2 = __half22float2(Tv[(size_t)col[e + 2] * 32 + c2]);
        float2 v3 = __half22float2(Tv[(size_t)col[e + 3] * 32 + c2]);
        acc.x += (v0.x + v1.x) + (v2.x + v3.x);
        acc.y += (v0.y + v1.y) + (v2.y + v3.y);
    }
    for (; e < end; ++e) {
        float2 v0 = __half22float2(Tv[(size_t)col[e] * 32 + c2]);
        acc.x += v0.x; acc.y += v0.y;
    }
    float w = dinv[node];
    float2 b = ((const float2*)b2)[c2];
    float vx = fmaf(w, acc.x, b.x);
    float vy = fmaf(w, acc.y, b.y);
    float m = fmaxf(vx, vy);
#pragma unroll
    for (int off = 16; off > 0; off >>= 1) m = fmaxf(m, __shfl_xor(m, off));
    float sum = __expf(vx - m) + __expf(vy - m);
#pragma unroll
    for (int off = 16; off > 0; off >>= 1) sum += __shfl_xor(sum, off);
    float ls = m + logf(sum);
    float2 o;
    o.x = vx - ls;
    o.y = vy - ls;
    ((float2*)OUT)[(size_t)node * 32 + c2] = o;
}

extern "C" void kernel_launch(void* const* d_in, const int* in_sizes, int n_in,
                              void* d_out, int out_size, void* d_ws, size_t ws_size,
                              hipStream_t stream) {
    const float* x   = (const float*)d_in[0];
    const int*   ei  = (const int*)d_in[1];   // int32 per harness contract
    const float* W1  = (const float*)d_in[2];
    const float* b1  = (const float*)d_in[3];
    const float* W2  = (const float*)d_in[4];
    const float* b2  = (const float*)d_in[5];
    float*       out = (float*)d_out;

    const int N = in_sizes[0] / 128;      // 100000
    const int E = in_sizes[1] / 2;        // 1600000
    const int* src = ei;
    const int* dst = ei + E;
    const int NB = (N + BSIZE - 1) >> BSHIFT;   // dst buckets (196 <= 256)

    // workspace layout
    char* ws = (char*)d_ws;
    size_t off = 0;
    auto alloc = [&](size_t bytes) { void* p = ws + off; off = (off + bytes + 255) & ~(size_t)255; return p; };
    unsigned int* deg    = (unsigned int*)alloc((size_t)N * 4);
    float*        dinv   = (float*)alloc((size_t)N * 4);
    unsigned int* cursor = (unsigned int*)alloc((size_t)N * 4);
    unsigned int* bcount = (unsigned int*)alloc(256 * 4);
    unsigned int* bb     = (unsigned int*)alloc(257 * 4);       // bucket_base
    unsigned int* bf     = (unsigned int*)alloc(256 * 4);       // bucket_fill
    __half*       w1s    = (__half*)alloc(128 * 128 * 2);       // swizzled W1
    __half*       w2s    = (__half*)alloc(128 * 64 * 2);        // swizzled W2
    int*          col    = (int*)alloc((size_t)E * 4);
    __half*       A      = (__half*)alloc((size_t)N * 128 * 2); // T1' fp16
    __half*       B      = (__half*)alloc((size_t)N * 64 * 2);  // T2' fp16
    unsigned int* ebuf   = (unsigned int*)alloc((size_t)E * 4);

    // 1. CSR build: bucket hist -> scan -> partition -> per-bucket scatter
    hipMemsetAsync(bcount, 0, 256 * 4, stream);
    bucket_hist_kernel<<<(E + 4095) / 4096, 256, 0, stream>>>(dst, E, bcount, NB);
    bucket_scan_kernel<<<1, 256, 0, stream>>>(bcount, bb, bf, NB, E);
    partition_kernel<<<(E + P2_T * P2_I - 1) / (P2_T * P2_I), P2_T, 0, stream>>>(src, dst, bf, ebuf, E, NB);
    bucket_scatter2_kernel<<<NB, 256, 0, stream>>>(ebuf, bb, cursor, deg, dinv, col, N);
    // now cursor[i] == rowend(i); rowstart(i) = cursor[i] - deg[i]; dinv ready

    // 1b. swizzle weights into MFMA fragment order
    swizzle_w_kernel<<<1, 256, 0, stream>>>(W1, W2, w1s, w2s);

    // 2. T1' = dinv * (x @ W1) [MFMA fp16]
    gemm1_mfma_kernel<<<(N + 63) / 64, 256, 0, stream>>>(x, w1s, dinv, A, N);

    // 3. fused: h = relu(dinv*(pull T1') + b1) -> LDS;  T2' = dinv*(h @ W2)
    pull1_fused_kernel<<<(N + 15) / 16, 1024, 0, stream>>>(A, col, cursor, deg, dinv, b1, w2s, B, N);

    // 4. out = logsoftmax(dinv*(pull T2') + b2)
    pull_agg2_kernel<<<(N + 7) / 8, 256, 0, stream>>>(B, col, cursor, deg, dinv, b2, out, N);
}